// Round 3
// baseline (209.446 us; speedup 1.0000x reference)
//
#include <hip/hip_runtime.h>

// SpatialAttention fp32: B=128, C=3, H=W=256, 8x8 patches, FEAT=192, ENC=16.
// R7: attack the SMEM bottleneck. Evidence: occupancy 41%->72% (R4->R6) moved
// VALUBusy only 26%->35% -- waves stall on a shared resource. Theory: scalar
// weight delivery. Each s_loaded weight dword feeds exactly ONE fma (reuse=1);
// 96 s_load_dwordx8/wave at ~150cy through a thrashed 16KB sK$ (weights=25KB)
// vs 3.8k cy of VALU work = ~50% stall, TLP-insensitive.
// Fix: 2 patches per lane (p and p+64). Same weight stream feeds 2x the FMAs
// -> SMEM stall fraction halves. 8 waves x 24 features as R6.
// Cost: regs ~92 peak and encl=64KB -> __launch_bounds__(512,4): VGPR cap 128
// (margin ~36; R5 lesson: stay well under cap), 2 blocks/CU (137KB LDS), 16
// waves/CU (~50% occupancy -- intentional: this A/Bs SMEM-theory vs occupancy).
// Spill tripwire: WRITE_SIZE must be ~98-100MB and VGPR_Count ~96-112.

constexpr int NPATCH = 128 * 32 * 32;
constexpr float L2E  = 1.4426950408889634f;

__global__ __launch_bounds__(512, 4) void spatial_attn(
    const float* __restrict__ x,      // [128][3][256][256]
    const float* __restrict__ Wenc,   // [16][192]
    const float* __restrict__ benc,   // [16]
    const float* __restrict__ Wdec,   // [192][16]
    const float* __restrict__ bdec,   // [192]
    float* __restrict__ y)            // [128][3][256][256]
{
  __shared__ float encl[16 * 1024];   // [e][pset(2)][512tid] = 64KB
  __shared__ float sls[1024];         // [pset][512] softmax partials

  const int tid  = threadIdx.x;
  const int lane = tid & 63;
  const int wv   = __builtin_amdgcn_readfirstlane(tid >> 6);  // uniform
  // Block owns 128 patches: set0 = blk*128+lane, set1 = blk*128+64+lane.
  const int p0   = blockIdx.x * 128 + lane;
  const int b    = p0 >> 10;
  const int ii   = (p0 >> 5) & 31;
  const int jj   = p0 & 31;
  const size_t base0 = (size_t)b * 196608 + (size_t)ii * 2048 + (size_t)jj * 8;
  const size_t base1 = base0 + 4096;  // p0+64 -> ii+2, same b (128 | 1024)

  // ---- Load both patches' 24 features (rows 3wv..3wv+2), float4 ----
  float xa[24], xb[24];
  #pragma unroll
  for (int t = 0; t < 3; ++t) {
    const int cr = 3 * wv + t;
    const size_t off = (size_t)(cr >> 3) * 65536 + (size_t)(cr & 7) * 256;
    const float4 a0 = *(const float4*)(x + base0 + off);
    const float4 a1 = *(const float4*)(x + base0 + off + 4);
    const float4 c0 = *(const float4*)(x + base1 + off);
    const float4 c1 = *(const float4*)(x + base1 + off + 4);
    xa[t*8+0]=a0.x; xa[t*8+1]=a0.y; xa[t*8+2]=a0.z; xa[t*8+3]=a0.w;
    xa[t*8+4]=a1.x; xa[t*8+5]=a1.y; xa[t*8+6]=a1.z; xa[t*8+7]=a1.w;
    xb[t*8+0]=c0.x; xb[t*8+1]=c0.y; xb[t*8+2]=c0.z; xb[t*8+3]=c0.w;
    xb[t*8+4]=c1.x; xb[t*8+5]=c1.y; xb[t*8+6]=c1.z; xb[t*8+7]=c1.w;
  }

  // ---- Encoder: each s_loaded 24-weight chunk feeds BOTH patches ----
  #pragma unroll
  for (int e = 0; e < 16; ++e) {
    const float* w = Wenc + e * 192 + wv * 24;   // wave-uniform -> s_load
    float a = 0.0f, c = 0.0f;
    #pragma unroll
    for (int q = 0; q < 24; ++q) {
      a = fmaf(w[q], xa[q], a);
      c = fmaf(w[q], xb[q], c);
    }
    encl[e * 1024 + tid]       = a;              // pset0
    encl[e * 1024 + 512 + tid] = c;              // pset1
  }
  __syncthreads();

  // ---- Cross-wave reduce (8 partials per e, both patches) ----
  float h0[16], h1[16];
  #pragma unroll
  for (int e = 0; e < 16; ++e) {
    const float* c0 = encl + e * 1024 + lane;
    const float* c1 = c0 + 512;
    float a = c0[0], c = c1[0];
    #pragma unroll
    for (int w8 = 1; w8 < 8; ++w8) { a += c0[w8 * 64]; c += c1[w8 * 64]; }
    const float be = benc[e];
    h0[e] = fmaxf(a + be, 0.0f);
    h1[e] = fmaxf(c + be, 0.0f);
  }

  // ---- Decoder: each s_loaded 16-weight row feeds BOTH patches ----
  float o0[24], o1[24];
  float s0 = 0.0f, s1 = 0.0f;
  #pragma unroll
  for (int q = 0; q < 24; ++q) {
    const int f = wv * 24 + q;
    const float* w = Wdec + f * 16;              // wave-uniform -> s_load
    const float bf = bdec[f];
    float v0 = bf, v1 = bf;
    #pragma unroll
    for (int e = 0; e < 16; ++e) {
      v0 = fmaf(w[e], h0[e], v0);
      v1 = fmaf(w[e], h1[e], v1);
    }
    v0 = fmaxf(v0, 0.0f); v1 = fmaxf(v1, 0.0f);
    o0[q] = v0; o1[q] = v1;
    s0 += __builtin_amdgcn_exp2f(v0 * L2E);      // out>=0, bounded: no max-sub
    s1 += __builtin_amdgcn_exp2f(v1 * L2E);
  }

  // ---- Softmax denominators across the 8 waves, both patches ----
  sls[tid] = s0; sls[512 + tid] = s1;
  __syncthreads();
  float st0 = sls[lane], st1 = sls[512 + lane];
  #pragma unroll
  for (int w8 = 1; w8 < 8; ++w8) {
    st0 += sls[w8 * 64 + lane];
    st1 += sls[512 + w8 * 64 + lane];
  }
  const float inv0 = __builtin_amdgcn_rcpf(st0);
  const float inv1 = __builtin_amdgcn_rcpf(st1);

  // ---- y = softmax(out)*out, coalesced float4 stores, both patches ----
  #pragma unroll
  for (int t = 0; t < 3; ++t) {
    const int cr = 3 * wv + t;
    const size_t off = (size_t)(cr >> 3) * 65536 + (size_t)(cr & 7) * 256;
    float r[8], u[8];
    #pragma unroll
    for (int c = 0; c < 8; ++c) {
      const float va = o0[t * 8 + c];
      const float vb = o1[t * 8 + c];
      r[c] = __builtin_amdgcn_exp2f(va * L2E) * inv0 * va;
      u[c] = __builtin_amdgcn_exp2f(vb * L2E) * inv1 * vb;
    }
    float* d0 = y + base0 + off;
    float* d1 = y + base1 + off;
    *(float4*)(d0)     = (float4){r[0], r[1], r[2], r[3]};
    *(float4*)(d0 + 4) = (float4){r[4], r[5], r[6], r[7]};
    *(float4*)(d1)     = (float4){u[0], u[1], u[2], u[3]};
    *(float4*)(d1 + 4) = (float4){u[4], u[5], u[6], u[7]};
  }
}

extern "C" void kernel_launch(void* const* d_in, const int* in_sizes, int n_in,
                              void* d_out, int out_size, void* d_ws, size_t ws_size,
                              hipStream_t stream) {
  const float* x    = (const float*)d_in[0];
  const float* Wenc = (const float*)d_in[1];
  const float* benc = (const float*)d_in[2];
  const float* Wdec = (const float*)d_in[3];
  const float* bdec = (const float*)d_in[4];
  float* y = (float*)d_out;
  dim3 grid(NPATCH / 128), block(512);
  hipLaunchKernelGGL(spatial_attn, grid, block, 0, stream, x, Wenc, benc, Wdec, bdec, y);
}

// Round 4
// 192.751 us; speedup vs baseline: 1.0866x; 1.0866x over previous
//
#include <hip/hip_runtime.h>

// SpatialAttention fp32: B=128, C=3, H=W=256, 8x8 patches, FEAT=192, ENC=16.
// R8: kill the scalar-cache thrash. Evidence chain: VALUBusy pinned ~33-35%
// regardless of occupancy (R6: 71% occ) or per-wave weight reuse (R7: 2
// patches/lane) -> the stall is a shared serializing resource. Theory: s_load
// working set Wenc+Wdec+biases = 25.4KB > 16KB sK$ -> perpetual miss traffic
// through the scalar pipe for every resident wave.
// Fix: stage Wenc (12.3KB) + both biases in LDS once per block; encoder reads
// weights via lane-uniform ds_read (HW broadcast, conflict-free, DS pipe is
// idle). Decoder keeps s_load: its 12.3KB now fits sK$ alone.
// Skeleton = R6 (best, 77.5us): 8 waves x 24 features, 1 patch/lane.
// LDS 47.9KB -> 3 blocks/CU = 24 waves/CU; __launch_bounds__(512,6) caps
// VGPR at 84 (peak liveness ~70). Tripwires: VGPR 80-84 & WRITE ~106MB good;
// VGPR=64 or WRITE>120MB = allocator throttle/spill -> revert to (512,4).

constexpr int NPATCH = 128 * 32 * 32;
constexpr float L2E  = 1.4426950408889634f;

__global__ __launch_bounds__(512, 6) void spatial_attn(
    const float* __restrict__ x,      // [128][3][256][256]
    const float* __restrict__ Wenc,   // [16][192]
    const float* __restrict__ benc,   // [16]
    const float* __restrict__ Wdec,   // [192][16]
    const float* __restrict__ bdec,   // [192]
    float* __restrict__ y)            // [128][3][256][256]
{
  __shared__ float encl[16 * 512];    // [e][tid] encoder partials  (32 KB)
  __shared__ float wencl[16 * 192];   // staged Wenc                (12 KB)
  __shared__ float biasl[208];        // benc[0..15], bdec[0..191]  (832 B)
  __shared__ float sls[512];          // softmax partials           (2 KB)

  const int tid  = threadIdx.x;
  const int lane = tid & 63;
  const int wv   = __builtin_amdgcn_readfirstlane(tid >> 6);  // uniform
  const int p    = blockIdx.x * 64 + lane;                    // one patch/lane
  const int b    = p >> 10;
  const int ii   = (p >> 5) & 31;
  const int jj   = p & 31;
  const size_t base = (size_t)b * 196608 + (size_t)ii * 2048 + (size_t)jj * 8;

  // ---- Stage Wenc + biases into LDS (coalesced, 6+1 dwords/thread) ----
  #pragma unroll
  for (int t = 0; t < 6; ++t) wencl[t * 512 + tid] = Wenc[t * 512 + tid];
  if (tid < 208) biasl[tid] = (tid < 16) ? benc[tid] : bdec[tid - 16];

  // ---- Load this wave's 24 features (rows 3wv..3wv+2), coalesced float4 ----
  // (private data: does not need the staging barrier)
  float xv[24];
  #pragma unroll
  for (int t = 0; t < 3; ++t) {
    const int cr = 3 * wv + t;
    const float* src = x + base + (cr >> 3) * 65536 + (cr & 7) * 256;
    const float4 v0 = *(const float4*)(src);
    const float4 v1 = *(const float4*)(src + 4);
    xv[t*8+0]=v0.x; xv[t*8+1]=v0.y; xv[t*8+2]=v0.z; xv[t*8+3]=v0.w;
    xv[t*8+4]=v1.x; xv[t*8+5]=v1.y; xv[t*8+6]=v1.z; xv[t*8+7]=v1.w;
  }
  __syncthreads();                     // wencl/biasl visible

  // ---- Encoder partial over 24 features; weights via LDS broadcast ----
  #pragma unroll
  for (int e = 0; e < 16; ++e) {
    const float* w = wencl + e * 192 + wv * 24;  // lane-uniform -> broadcast
    float a = 0.0f;
    #pragma unroll
    for (int q = 0; q < 24; ++q) a = fmaf(w[q], xv[q], a);
    encl[e * 512 + tid] = a;                     // one acc live at a time
  }
  __syncthreads();

  // ---- Cross-wave reduce (8 partials per e), bias + relu ----
  float h[16];
  #pragma unroll
  for (int e = 0; e < 16; ++e) {
    const float* c = encl + e * 512 + lane;
    float a = c[0];
    #pragma unroll
    for (int w8 = 1; w8 < 8; ++w8) a += c[w8 * 64];
    h[e] = fmaxf(a + biasl[e], 0.0f);
  }

  // ---- Decoder: 24 outputs in registers; Wdec via s_load (fits sK$ now) ----
  float o[24];
  float s = 0.0f;
  #pragma unroll
  for (int q = 0; q < 24; ++q) {
    const int f = wv * 24 + q;
    const float* w = Wdec + f * 16;              // wave-uniform -> s_load
    float v = biasl[16 + f];
    #pragma unroll
    for (int e = 0; e < 16; ++e) v = fmaf(w[e], h[e], v);
    v = fmaxf(v, 0.0f);
    o[q] = v;
    s += __builtin_amdgcn_exp2f(v * L2E);        // out>=0, bounded: no max-sub
  }

  // ---- Softmax denominator across the 8 waves ----
  sls[tid] = s;
  __syncthreads();
  float st = sls[lane];
  #pragma unroll
  for (int w8 = 1; w8 < 8; ++w8) st += sls[w8 * 64 + lane];
  const float inv = __builtin_amdgcn_rcpf(st);

  // ---- y = softmax(out)*out, coalesced float4 stores ----
  #pragma unroll
  for (int t = 0; t < 3; ++t) {
    const int cr = 3 * wv + t;
    float* dst = y + base + (cr >> 3) * 65536 + (cr & 7) * 256;
    float r[8];
    #pragma unroll
    for (int c = 0; c < 8; ++c) {
      const float ov = o[t * 8 + c];
      r[c] = __builtin_amdgcn_exp2f(ov * L2E) * inv * ov;
    }
    const float4 s0 = {r[0], r[1], r[2], r[3]};
    const float4 s1 = {r[4], r[5], r[6], r[7]};
    *(float4*)(dst)     = s0;
    *(float4*)(dst + 4) = s1;
  }
}

extern "C" void kernel_launch(void* const* d_in, const int* in_sizes, int n_in,
                              void* d_out, int out_size, void* d_ws, size_t ws_size,
                              hipStream_t stream) {
  const float* x    = (const float*)d_in[0];
  const float* Wenc = (const float*)d_in[1];
  const float* benc = (const float*)d_in[2];
  const float* Wdec = (const float*)d_in[3];
  const float* bdec = (const float*)d_in[4];
  float* y = (float*)d_out;
  dim3 grid(NPATCH / 64), block(512);
  hipLaunchKernelGGL(spatial_attn, grid, block, 0, stream, x, Wenc, benc, Wdec, bdec, y);
}

// Round 5
// 192.497 us; speedup vs baseline: 1.0880x; 1.0013x over previous
//
#include <hip/hip_runtime.h>

// SpatialAttention fp32: B=128, C=3, H=W=256, 8x8 patches, FEAT=192, ENC=16.
// R9: weights -> wave-private VGPRs, delivered by v_readlane (per-SIMD VALU),
// eliminating per-use weight traffic on the per-CU shared pipes.
// Evidence: VALUBusy pinned 33-36% / dur 78-86us across occupancy 37->88%,
// reuse 1->2, s_load->LDS delivery (R6/R7/R8). Every wave re-fetched 768
// weight dwords through a per-CU pipe (SALU or DS), ~1-2k cy/wave x 64
// waves/CU ~= 50us/CU invariant floor.
// Fix: a wave touches only its 24-feature slice = 384+384 dwords = 12 VGPRs.
//  - we[16]: lane q<24 holds Wenc[e][wv*24+q]   (16 loads, lanes>=24 clamped)
//  - wd[6]:  lane l holds Wdec[wv*384 + 64k + l] (contiguous, coalesced)
//  - weight at (e,q): rdlane(we[e], q); at (q,e): rdlane(wd[(16q+e)>>6],
//    (16q+e)&63) -- all lane indices compile-time (full unroll) -> SGPR
//    operand of v_fmac. Zero weight memory traffic after preload.
// Also de-duplicate the reduce: wave wv reduces e={2wv,2wv+1} only, stages
// h in hl[16][64]; DS drops 128->~34 reads/thread.
// Regs: we16+wd6+xv24+h16+o24 ~= 101 peak -> __launch_bounds__(512,4),
// cap 128, margin ~27. LDS 38.9KB. Occupancy ~50% (intentional; latency
// demand is now small). Tripwire: VGPR 96-112 & WRITE ~98MB; VGPR=64 or
// WRITE>110MB = throttle/spill -> loosen to (512,2) next.

constexpr int NPATCH = 128 * 32 * 32;
constexpr float L2E  = 1.4426950408889634f;

__device__ __forceinline__ float rdlane(float v, int l) {
  return __uint_as_float(__builtin_amdgcn_readlane(__float_as_uint(v), l));
}

__global__ __launch_bounds__(512, 4) void spatial_attn(
    const float* __restrict__ x,      // [128][3][256][256]
    const float* __restrict__ Wenc,   // [16][192]
    const float* __restrict__ benc,   // [16]
    const float* __restrict__ Wdec,   // [192][16]
    const float* __restrict__ bdec,   // [192]
    float* __restrict__ y)            // [128][3][256][256]
{
  __shared__ float encl[16 * 512];    // [e][tid] encoder partials (32 KB)
  __shared__ float hl[16 * 64];       // [e][patch-lane] relu'd h   (4 KB)
  __shared__ float sls[512];          // softmax partials           (2 KB)

  const int tid  = threadIdx.x;
  const int lane = tid & 63;
  const int wv   = __builtin_amdgcn_readfirstlane(tid >> 6);  // uniform
  const int p    = blockIdx.x * 64 + lane;                    // one patch/lane
  const int b    = p >> 10;
  const int ii   = (p >> 5) & 31;
  const int jj   = p & 31;
  const size_t base = (size_t)b * 196608 + (size_t)ii * 2048 + (size_t)jj * 8;

  // ---- Preload this wave's weight slices into VGPRs (once) ----
  float we[16];                       // Wenc[e][wv*24 + (lane<24?lane:0)]
  const int col = (lane < 24) ? lane : 0;   // clamp: avoid OOB, junk unused
  #pragma unroll
  for (int e = 0; e < 16; ++e) we[e] = Wenc[e * 192 + wv * 24 + col];
  float wd[6];                        // Wdec slice: 384 contiguous dwords
  #pragma unroll
  for (int k = 0; k < 6; ++k) wd[k] = Wdec[wv * 384 + k * 64 + lane];

  // ---- Load this wave's 24 features (rows 3wv..3wv+2), coalesced float4 ----
  float xv[24];
  #pragma unroll
  for (int t = 0; t < 3; ++t) {
    const int cr = 3 * wv + t;
    const float* src = x + base + (cr >> 3) * 65536 + (cr & 7) * 256;
    const float4 v0 = *(const float4*)(src);
    const float4 v1 = *(const float4*)(src + 4);
    xv[t*8+0]=v0.x; xv[t*8+1]=v0.y; xv[t*8+2]=v0.z; xv[t*8+3]=v0.w;
    xv[t*8+4]=v1.x; xv[t*8+5]=v1.y; xv[t*8+6]=v1.z; xv[t*8+7]=v1.w;
  }

  // ---- Encoder partial over 24 features; weights via readlane (VALU) ----
  #pragma unroll
  for (int e = 0; e < 16; ++e) {
    float a = 0.0f;
    #pragma unroll
    for (int q = 0; q < 24; ++q) a = fmaf(rdlane(we[e], q), xv[q], a);
    encl[e * 512 + tid] = a;          // one acc live at a time
  }
  __syncthreads();

  // ---- Cross-wave reduce, de-duplicated: wave wv owns e = 2wv, 2wv+1 ----
  #pragma unroll
  for (int t = 0; t < 2; ++t) {
    const int e = 2 * wv + t;
    const float* c = encl + e * 512 + lane;
    float a = c[0];
    #pragma unroll
    for (int w8 = 1; w8 < 8; ++w8) a += c[w8 * 64];
    hl[e * 64 + lane] = fmaxf(a + benc[e], 0.0f);   // benc: tiny, sK$-hot
  }
  __syncthreads();

  // ---- All waves pick up h[16] for their patch (16 b32, conflict-free) ----
  float h[16];
  #pragma unroll
  for (int e = 0; e < 16; ++e) h[e] = hl[e * 64 + lane];

  // ---- Decoder: 24 outputs in registers; weights via readlane (VALU) ----
  float o[24];
  float s = 0.0f;
  #pragma unroll
  for (int q = 0; q < 24; ++q) {
    const int f = wv * 24 + q;
    float v = bdec[f];                // tiny, sK$-hot
    #pragma unroll
    for (int e = 0; e < 16; ++e) {
      const int idx = q * 16 + e;     // compile-time
      v = fmaf(rdlane(wd[idx >> 6], idx & 63), h[e], v);
    }
    v = fmaxf(v, 0.0f);
    o[q] = v;
    s += __builtin_amdgcn_exp2f(v * L2E);   // out>=0, bounded: no max-sub
  }

  // ---- Softmax denominator across the 8 waves ----
  sls[tid] = s;
  __syncthreads();
  float st = sls[lane];
  #pragma unroll
  for (int w8 = 1; w8 < 8; ++w8) st += sls[w8 * 64 + lane];
  const float inv = __builtin_amdgcn_rcpf(st);

  // ---- y = softmax(out)*out, coalesced float4 stores ----
  #pragma unroll
  for (int t = 0; t < 3; ++t) {
    const int cr = 3 * wv + t;
    float* dst = y + base + (cr >> 3) * 65536 + (cr & 7) * 256;
    float r[8];
    #pragma unroll
    for (int c = 0; c < 8; ++c) {
      const float ov = o[t * 8 + c];
      r[c] = __builtin_amdgcn_exp2f(ov * L2E) * inv * ov;
    }
    const float4 s0 = {r[0], r[1], r[2], r[3]};
    const float4 s1 = {r[4], r[5], r[6], r[7]};
    *(float4*)(dst)     = s0;
    *(float4*)(dst + 4) = s1;
  }
}

extern "C" void kernel_launch(void* const* d_in, const int* in_sizes, int n_in,
                              void* d_out, int out_size, void* d_ws, size_t ws_size,
                              hipStream_t stream) {
  const float* x    = (const float*)d_in[0];
  const float* Wenc = (const float*)d_in[1];
  const float* benc = (const float*)d_in[2];
  const float* Wdec = (const float*)d_in[3];
  const float* bdec = (const float*)d_in[4];
  float* y = (float*)d_out;
  dim3 grid(NPATCH / 64), block(512);
  hipLaunchKernelGGL(spatial_attn, grid, block, 0, stream, x, Wenc, benc, Wdec, bdec, y);
}